// Round 1
// baseline (783.159 us; speedup 1.0000x reference)
//
#include <hip/hip_runtime.h>
#include <math.h>

#ifndef M_PI
#define M_PI 3.14159265358979323846
#endif

#define NN 128
#define NI 126
#define MM_ 128
#define BB 8

// sigma_gamma(r) = (SP-SM)*sigmoid(r/DSIG)+SM, SP=1/12, SM=-1/3, DSIG=0.15
__device__ __forceinline__ float sigma_gamma(float r) {
    float s = 1.0f / (1.0f + __expf(r * (-1.0f / 0.15f)));
    return 0.4166666666666667f * s - 0.3333333333333333f;
}

// Fill sine matrix S (126x126 valid, zero-padded to 128x128) and DENINV.
// poisson_solve(R) = S * ((S*R*S) .* DENINV) * S  on the interior,
// DENINV = 16 / (4*127*127 * DENOM),  DENOM = (lam_k + lam_l)/H^2,
// lam_k = 4 sin^2(pi k / 254), H = 1/127.
__global__ __launch_bounds__(256) void k_prep(float* __restrict__ S,
                                              float* __restrict__ DINV) {
    int id = blockIdx.x * blockDim.x + threadIdx.x;
    if (id >= NN * NN) return;
    int r = id >> 7, c = id & 127;
    float s = 0.f, di = 0.f;
    if (r < NI && c < NI) {
        int prod = ((r + 1) * (c + 1)) % 254;
        s = sinf((float)prod * (float)(M_PI / 127.0));
        float sr = sinf((float)(r + 1) * (float)(M_PI / 254.0));
        float sc = sinf((float)(c + 1) * (float)(M_PI / 254.0));
        float lam = 4.f * (sr * sr + sc * sc);           // lam_r + lam_c
        di = 16.0f / (64516.0f * 16129.0f * lam);
    }
    S[id] = s;
    DINV[id] = di;
}

// 34 Jacobi diffusion steps (Neumann/replicate BC) per batch b, then
// inva = 1/a_eps, loga = log(max(a_eps,eps)), central-diff gradients
// (only interior values are ever consumed downstream).
__global__ __launch_bounds__(1024) void k_smooth(const float* __restrict__ a,
                                                 float* __restrict__ inva,
                                                 float* __restrict__ dlx,
                                                 float* __restrict__ dly) {
    __shared__ float U[NN * NN];
    __shared__ float V[NN * NN];
    int b = blockIdx.x;
    const float* ab = a + b * NN * NN;
    for (int k = threadIdx.x; k < NN * NN; k += 1024) U[k] = ab[k];
    __syncthreads();
    float* cur = U;
    float* nxt = V;
    const float CC = 0.03f * 1e-4f * 16129.0f;  // DT*ETA/H^2
    for (int it = 0; it < 34; ++it) {
        for (int k = threadIdx.x; k < NN * NN; k += 1024) {
            int r = k >> 7, c = k & 127;
            float u = cur[k];
            float un = cur[(r > 0 ? r - 1 : 0) * NN + c];
            float us = cur[(r < 127 ? r + 1 : 127) * NN + c];
            float uw = cur[r * NN + (c > 0 ? c - 1 : 0)];
            float ue = cur[r * NN + (c < 127 ? c + 1 : 127)];
            nxt[k] = u + CC * (un + us + uw + ue - 4.f * u);
        }
        __syncthreads();
        float* t = cur; cur = nxt; nxt = t;
    }
    // cur = a_eps
    for (int k = threadIdx.x; k < NN * NN; k += 1024) {
        float ae = cur[k];
        inva[b * NN * NN + k] = 1.0f / ae;
        nxt[k] = logf(fmaxf(ae, 1e-9f));
    }
    __syncthreads();
    for (int k = threadIdx.x; k < NN * NN; k += 1024) {
        int r = k >> 7, c = k & 127;
        float gx = 0.f, gy = 0.f;
        if (r >= 1 && r <= 126 && c >= 1 && c <= 126) {
            gx = 63.5f * (nxt[k + NN] - nxt[k - NN]);  // 1/(2H) = 63.5
            gy = 63.5f * (nxt[k + 1] - nxt[k - 1]);
        }
        dlx[b * NN * NN + k] = gx;
        dly[b * NN * NN + k] = gy;
    }
}

// S1a[x,y] = sum_m alpha_m * sigma(theta1[m,x,y])
__global__ __launch_bounds__(256) void k_s1a(const float* __restrict__ theta1,
                                             const float* __restrict__ alpha,
                                             float* __restrict__ S1a) {
    int id = blockIdx.x * blockDim.x + threadIdx.x;
    if (id >= NN * NN) return;
    float acc = 0.f;
    for (int m = 0; m < MM_; ++m)
        acc += alpha[m] * sigma_gamma(theta1[m * NN * NN + id]);
    S1a[id] = acc;
}

// Fused per-grid Poisson solve: 4 chained 128^3 matmuls in one block,
// single 64KB LDS matrix buffer (in-place after barrier) + 8KB S-chunk.
// STAGE 1: grid = B*M blocks; R = sigma(theta1_m)*inva_b; epilogue computes
//          t = alpha_m * sigma(theta2_m) * (dlx*g0x + dly*g0y) -> t_all.
// STAGE 2: grid = B blocks; R = R2 (pre-reduced rhs); epilogue writes d_out.
template <int STAGE>
__global__ __launch_bounds__(256) void k_poisson(
    const float* __restrict__ Sg, const float* __restrict__ DINV,
    const float* __restrict__ theta1, const float* __restrict__ theta2,
    const float* __restrict__ alpha, const float* __restrict__ inva,
    const float* __restrict__ dlx, const float* __restrict__ dly,
    const float* __restrict__ R2, float* __restrict__ t_all,
    float* __restrict__ outp) {
    __shared__ float X[NN * NN];   // 64 KB
    __shared__ float CH[16 * NN];  // 8 KB: 16 rows of S
    int b, m;
    if (STAGE == 1) { b = blockIdx.x & 7; m = blockIdx.x >> 3; }
    else            { b = blockIdx.x;     m = 0; }
    const int tid = threadIdx.x;
    const int tx = tid & 15, ty = tid >> 4;

    // ---- load R into X (zero-padded beyond 126x126 interior) ----
    if (STAGE == 1) {
        const float* th1 = theta1 + m * NN * NN;
        const float* iv = inva + b * NN * NN;
        for (int k = tid; k < NN * NN; k += 256) {
            int r = k >> 7, c = k & 127;
            float v = 0.f;
            if (r < NI && c < NI) {
                int fi = (r + 1) * NN + (c + 1);
                v = sigma_gamma(th1[fi]) * iv[fi];
            }
            X[k] = v;
        }
    } else {
        for (int k = tid; k < NN * NN; k += 256) X[k] = R2[b * NN * NN + k];
    }
    __syncthreads();

    float acc[8][8];
    // ---- 4 chained matmuls: mm0: S*X, mm1: X*S (+DENINV), mm2: S*X, mm3: X*S
    for (int mmi = 0; mmi < 4; ++mmi) {
        const bool aform = (mmi == 0 || mmi == 2);  // C = S*X (uses S symmetry)
#pragma unroll
        for (int rr = 0; rr < 8; ++rr)
#pragma unroll
            for (int cc = 0; cc < 8; ++cc) acc[rr][cc] = 0.f;

        for (int i0 = 0; i0 < NN; i0 += 16) {
            {   // stage 16 rows of S into CH
                int rr = tid >> 4;
                int cc = (tid & 15) * 8;
                const float4* src =
                    reinterpret_cast<const float4*>(Sg + (i0 + rr) * NN + cc);
                float4 v0 = src[0], v1 = src[1];
                float4* dst = reinterpret_cast<float4*>(CH + rr * NN + cc);
                dst[0] = v0; dst[1] = v1;
            }
            __syncthreads();
#pragma unroll
            for (int ii = 0; ii < 16; ++ii) {
                float aF[8], bF[8];
                if (aform) {
                    // A[r][i] = S[i][r] = CH[ii][r]; B[i][c] = X[i][c]
                    *(float4*)&aF[0] = *(const float4*)&CH[ii * NN + ty * 8];
                    *(float4*)&aF[4] = *(const float4*)&CH[ii * NN + ty * 8 + 4];
                    *(float4*)&bF[0] = *(const float4*)&X[(i0 + ii) * NN + tx * 8];
                    *(float4*)&bF[4] = *(const float4*)&X[(i0 + ii) * NN + tx * 8 + 4];
                } else {
                    // A[r][i] = X[r][i]; B[i][c] = S[i][c] = CH[ii][c]
#pragma unroll
                    for (int rr = 0; rr < 8; ++rr)
                        aF[rr] = X[(ty * 8 + rr) * NN + i0 + ii];
                    *(float4*)&bF[0] = *(const float4*)&CH[ii * NN + tx * 8];
                    *(float4*)&bF[4] = *(const float4*)&CH[ii * NN + tx * 8 + 4];
                }
#pragma unroll
                for (int rr = 0; rr < 8; ++rr)
#pragma unroll
                    for (int cc = 0; cc < 8; ++cc)
                        acc[rr][cc] = fmaf(aF[rr], bF[cc], acc[rr][cc]);
            }
            __syncthreads();
        }
        if (mmi == 1) {  // spectral solve: multiply by DENINV
#pragma unroll
            for (int rr = 0; rr < 8; ++rr) {
                const float* dp = &DINV[(ty * 8 + rr) * NN + tx * 8];
#pragma unroll
                for (int cc = 0; cc < 8; ++cc) acc[rr][cc] *= dp[cc];
            }
        }
        // write back in place (all reads of X finished at last barrier)
#pragma unroll
        for (int rr = 0; rr < 8; ++rr) {
            float4 w0 = make_float4(acc[rr][0], acc[rr][1], acc[rr][2], acc[rr][3]);
            float4 w1 = make_float4(acc[rr][4], acc[rr][5], acc[rr][6], acc[rr][7]);
            float4* dst = (float4*)&X[(ty * 8 + rr) * NN + tx * 8];
            dst[0] = w0; dst[1] = w1;
        }
        __syncthreads();
    }
    // X now holds U = p0 interior (rows/cols 0..125; pads are exactly zero)

    if (STAGE == 1) {
        const float* th2 = theta2 + m * NN * NN;
        const float alm = alpha[m];
        float* tb = t_all + (size_t)(b * MM_ + m) * NN * NN;
        const float* dlxb = dlx + b * NN * NN;
        const float* dlyb = dly + b * NN * NN;
        for (int k = tid; k < NN * NN; k += 256) {
            int r = k >> 7, c = k & 127;
            if (r < NI && c < NI) {
                int fi = (r + 1) * NN + (c + 1);
                float uxm = (r >= 1) ? X[k - NN] : 0.f;   // p0[fr-1]
                float uxp = X[k + NN];                    // p0[fr+1] (row126=0)
                float uym = (c >= 1) ? X[k - 1] : 0.f;
                float uyp = X[k + 1];
                float g0x = 63.5f * (uxp - uxm);
                float g0y = 63.5f * (uyp - uym);
                float s2 = sigma_gamma(th2[fi]);
                tb[k] = alm * s2 * (dlxb[fi] * g0x + dlyb[fi] * g0y);
            }
        }
    } else {
        float* ob = outp + b * NN * NN;
        for (int k = tid; k < NN * NN; k += 256) {
            int r = k >> 7, c = k & 127;
            float v = 0.f;
            if (r >= 1 && r <= 126 && c >= 1 && c <= 126)
                v = X[(r - 1) * NN + (c - 1)];
            ob[k] = v;
        }
    }
}

// R2[b,r,c] = inva*S1a (alpha-weighted rhs0 sum) + sum_m t_all[b,m,r,c]
__global__ __launch_bounds__(256) void k_reduce(const float* __restrict__ t_all,
                                                const float* __restrict__ inva,
                                                const float* __restrict__ S1a,
                                                float* __restrict__ R2) {
    int id = blockIdx.x * blockDim.x + threadIdx.x;
    if (id >= BB * NN * NN) return;
    int b = id >> 14;
    int k = id & 16383;
    int r = k >> 7, c = k & 127;
    float v = 0.f;
    if (r < NI && c < NI) {
        int fi = (r + 1) * NN + (c + 1);
        v = inva[b * NN * NN + fi] * S1a[fi];
        const float* tp = t_all + (size_t)b * MM_ * NN * NN + k;
        for (int m = 0; m < MM_; ++m) v += tp[(size_t)m * NN * NN];
    }
    R2[id] = v;
}

extern "C" void kernel_launch(void* const* d_in, const int* in_sizes, int n_in,
                              void* d_out, int out_size, void* d_ws,
                              size_t ws_size, hipStream_t stream) {
    const float* a      = (const float*)d_in[0];
    const float* theta1 = (const float*)d_in[1];
    const float* theta2 = (const float*)d_in[2];
    const float* alpha  = (const float*)d_in[3];
    float* out = (float*)d_out;

    float* w = (float*)d_ws;
    float* S    = w;                 // 16384
    float* DINV = w + 16384;         // 16384
    float* inva = w + 32768;         // 131072
    float* dlx  = w + 163840;        // 131072
    float* dly  = w + 294912;        // 131072
    float* S1a  = w + 425984;        // 16384
    float* R2   = w + 442368;        // 131072
    float* tall = w + 573440;        // 16777216 (B*M*128*128)

    k_prep<<<64, 256, 0, stream>>>(S, DINV);
    k_smooth<<<BB, 1024, 0, stream>>>(a, inva, dlx, dly);
    k_s1a<<<64, 256, 0, stream>>>(theta1, alpha, S1a);
    k_poisson<1><<<BB * MM_, 256, 0, stream>>>(S, DINV, theta1, theta2, alpha,
                                               inva, dlx, dly, nullptr, tall,
                                               nullptr);
    k_reduce<<<512, 256, 0, stream>>>(tall, inva, S1a, R2);
    k_poisson<2><<<BB, 256, 0, stream>>>(S, DINV, theta1, theta2, alpha, inva,
                                         dlx, dly, R2, tall, out);
}

// Round 2
// 367.196 us; speedup vs baseline: 2.1328x; 2.1328x over previous
//
#include <hip/hip_runtime.h>
#include <math.h>

#ifndef M_PI
#define M_PI 3.14159265358979323846
#endif

#define NN 128
#define NI 126
#define MM_ 128
#define BB 8
#define LDST 136  // padded LDS row stride (ushorts) for S tiles

typedef __attribute__((ext_vector_type(8))) short bf16x8;
typedef __attribute__((ext_vector_type(4))) float f32x4;

// sigma_gamma(r) = (SP-SM)*sigmoid(r/DSIG)+SM, SP=1/12, SM=-1/3, DSIG=0.15
__device__ __forceinline__ float sigma_gamma(float r) {
    float s = 1.0f / (1.0f + __expf(r * (-1.0f / 0.15f)));
    return 0.4166666666666667f * s - 0.3333333333333333f;
}

// split f32 -> bf16 hi (truncate) + bf16 lo (RNE of residual); hi+lo ~ 2^-17 rel
__device__ __forceinline__ void split1(float x, unsigned short& h, unsigned short& l) {
    unsigned u = __float_as_uint(x);
    unsigned hb = u & 0xffff0000u;
    h = (unsigned short)(hb >> 16);
    float d = x - __uint_as_float(hb);
    unsigned ud = __float_as_uint(d);
    l = (unsigned short)((ud + 0x7fffu + ((ud >> 16) & 1u)) >> 16);
}

__device__ __forceinline__ void split8(const f32x4 p0, const f32x4 p1,
                                       bf16x8& hi, bf16x8& lo) {
    float xs[8] = {p0.x, p0.y, p0.z, p0.w, p1.x, p1.y, p1.z, p1.w};
#pragma unroll
    for (int j = 0; j < 8; ++j) {
        unsigned short h, l;
        split1(xs[j], h, l);
        hi[j] = (short)h;
        lo[j] = (short)l;
    }
}

// Sine matrix S (126x126 valid, zero pad to 128) as bf16 hi/lo + DENINV (f32).
__global__ __launch_bounds__(256) void k_prep(unsigned short* __restrict__ Shi,
                                              unsigned short* __restrict__ Slo,
                                              float* __restrict__ DINV) {
    int id = blockIdx.x * blockDim.x + threadIdx.x;
    if (id >= NN * NN) return;
    int r = id >> 7, c = id & 127;
    float s = 0.f, di = 0.f;
    if (r < NI && c < NI) {
        int prod = ((r + 1) * (c + 1)) % 254;
        s = sinf((float)prod * (float)(M_PI / 127.0));
        float sr = sinf((float)(r + 1) * (float)(M_PI / 254.0));
        float sc = sinf((float)(c + 1) * (float)(M_PI / 254.0));
        float lam = 4.f * (sr * sr + sc * sc);
        di = 16.0f / (64516.0f * 16129.0f * lam);
    }
    unsigned short h, l;
    split1(s, h, l);
    Shi[id] = h;
    Slo[id] = l;
    DINV[id] = di;
}

// 34 Jacobi diffusion steps (replicate BC) per batch; then inva, log-gradients.
__global__ __launch_bounds__(1024) void k_smooth(const float* __restrict__ a,
                                                 float* __restrict__ inva,
                                                 float* __restrict__ dlx,
                                                 float* __restrict__ dly) {
    __shared__ float U[NN * NN];
    __shared__ float V[NN * NN];
    int b = blockIdx.x;
    const float* ab = a + b * NN * NN;
    for (int k = threadIdx.x; k < NN * NN; k += 1024) U[k] = ab[k];
    __syncthreads();
    float* cur = U;
    float* nxt = V;
    const float CC = 0.03f * 1e-4f * 16129.0f;  // DT*ETA/H^2
    for (int it = 0; it < 34; ++it) {
        for (int k = threadIdx.x; k < NN * NN; k += 1024) {
            int r = k >> 7, c = k & 127;
            float u = cur[k];
            float un = cur[(r > 0 ? r - 1 : 0) * NN + c];
            float us = cur[(r < 127 ? r + 1 : 127) * NN + c];
            float uw = cur[r * NN + (c > 0 ? c - 1 : 0)];
            float ue = cur[r * NN + (c < 127 ? c + 1 : 127)];
            nxt[k] = u + CC * (un + us + uw + ue - 4.f * u);
        }
        __syncthreads();
        float* t = cur; cur = nxt; nxt = t;
    }
    for (int k = threadIdx.x; k < NN * NN; k += 1024) {
        float ae = cur[k];
        inva[b * NN * NN + k] = 1.0f / ae;
        nxt[k] = logf(fmaxf(ae, 1e-9f));
    }
    __syncthreads();
    for (int k = threadIdx.x; k < NN * NN; k += 1024) {
        int r = k >> 7, c = k & 127;
        float gx = 0.f, gy = 0.f;
        if (r >= 1 && r <= 126 && c >= 1 && c <= 126) {
            gx = 63.5f * (nxt[k + NN] - nxt[k - NN]);
            gy = 63.5f * (nxt[k + 1] - nxt[k - 1]);
        }
        dlx[b * NN * NN + k] = gx;
        dly[b * NN * NN + k] = gy;
    }
}

// S1a[x,y] = sum_m alpha_m * sigma(theta1[m,x,y])
__global__ __launch_bounds__(256) void k_s1a(const float* __restrict__ theta1,
                                             const float* __restrict__ alpha,
                                             float* __restrict__ S1a) {
    int id = blockIdx.x * blockDim.x + threadIdx.x;
    if (id >= NN * NN) return;
    float acc = 0.f;
    for (int m = 0; m < MM_; ++m)
        acc += alpha[m] * sigma_gamma(theta1[m * NN * NN + id]);
    S1a[id] = acc;
}

// R[bm][r][k] = sigma(theta1[m])*inva[b] at interior (+1 shifted), 0 on pads.
// bm = b*128 + m. One thread = 8 consecutive k of one row.
__global__ __launch_bounds__(256) void k_genR(const float* __restrict__ theta1,
                                              const float* __restrict__ inva,
                                              float* __restrict__ R) {
    unsigned id = blockIdx.x * 256 + threadIdx.x;  // 2097152 total
    unsigned rowid = id >> 4;                      // 0..131071
    unsigned c0 = (id & 15) * 8;
    unsigned bm = rowid >> 7, r = rowid & 127;
    unsigned m = bm & 127, b = bm >> 7;
    float v[8];
    if (r < NI) {
        const float* t1 = theta1 + m * NN * NN + (r + 1) * NN + 1;
        const float* iv = inva + b * NN * NN + (r + 1) * NN + 1;
#pragma unroll
        for (int j = 0; j < 8; ++j) {
            unsigned c = c0 + j;
            v[j] = (c < NI) ? sigma_gamma(t1[c]) * iv[c] : 0.f;
        }
    } else {
#pragma unroll
        for (int j = 0; j < 8; ++j) v[j] = 0.f;
    }
    float* dst = R + (size_t)rowid * NN + c0;
    *(f32x4*)dst = f32x4{v[0], v[1], v[2], v[3]};
    *(f32x4*)(dst + 4) = f32x4{v[4], v[5], v[6], v[7]};
}

// Flat GEMM: C[(bm,r)][c] = sum_k A[(bm,r)][k] * S[k][c], stored TRANSPOSED
// per slice: O[bm][c][r] = C (optionally * DINV[c][r]).  A is f32, split to
// bf16 hi/lo in-register; S is staged bf16 hi/lo in LDS (padded stride).
// 512 threads = 8 waves; each wave owns 2x16-row strips; block = 256 rows
// = exactly 2 grid-slices. In-place (O==A) is safe: barrier before epilogue,
// and blocks only touch their own slices.
template <bool DODINV>
__global__ __launch_bounds__(512, 4) void k_gemm(
    const float* __restrict__ A, float* __restrict__ O,
    const unsigned short* __restrict__ Shi_g,
    const unsigned short* __restrict__ Slo_g,
    const float* __restrict__ DINVg) {
    __shared__ unsigned short SH[128 * LDST];
    __shared__ unsigned short SL[128 * LDST];
    const int tid = threadIdx.x;
    // stage S into LDS (8B chunks)
    for (int idx = tid * 4; idx < 16384; idx += 2048) {
        int r = idx >> 7, c = idx & 127;
        *(uint2*)&SH[r * LDST + c] = *(const uint2*)(Shi_g + idx);
        *(uint2*)&SL[r * LDST + c] = *(const uint2*)(Slo_g + idx);
    }
    __syncthreads();

    const int wave = tid >> 6, lane = tid & 63;
    const int l15 = lane & 15, lg = lane >> 4;

    f32x4 acc[2][8];
#pragma unroll
    for (int s = 0; s < 2; ++s)
#pragma unroll
        for (int n = 0; n < 8; ++n) acc[s][n] = f32x4{0.f, 0.f, 0.f, 0.f};

    const unsigned blkrow = blockIdx.x * 256;
    const float* a0 = A + (size_t)(blkrow + wave * 32 + l15) * NN + lg * 8;
    const float* a1 = a0 + 16 * NN;

#pragma unroll
    for (int kk = 0; kk < 4; ++kk) {
        const int kb = kk * 32;
        bf16x8 ah0, al0, ah1, al1;
        {
            f32x4 p0 = *(const f32x4*)(a0 + kb);
            f32x4 p1 = *(const f32x4*)(a0 + kb + 4);
            split8(p0, p1, ah0, al0);
            f32x4 q0 = *(const f32x4*)(a1 + kb);
            f32x4 q1 = *(const f32x4*)(a1 + kb + 4);
            split8(q0, q1, ah1, al1);
        }
#pragma unroll
        for (int n = 0; n < 8; ++n) {
            const int col = n * 16 + l15;
            const int soff = col * LDST + kb + lg * 8;
            bf16x8 bh = *(const bf16x8*)&SH[soff];
            bf16x8 bl = *(const bf16x8*)&SL[soff];
            acc[0][n] = __builtin_amdgcn_mfma_f32_16x16x32_bf16(ah0, bh, acc[0][n], 0, 0, 0);
            acc[0][n] = __builtin_amdgcn_mfma_f32_16x16x32_bf16(ah0, bl, acc[0][n], 0, 0, 0);
            acc[0][n] = __builtin_amdgcn_mfma_f32_16x16x32_bf16(al0, bh, acc[0][n], 0, 0, 0);
            acc[0][n] = __builtin_amdgcn_mfma_f32_16x16x32_bf16(al0, bl, acc[0][n], 0, 0, 0);
            acc[1][n] = __builtin_amdgcn_mfma_f32_16x16x32_bf16(ah1, bh, acc[1][n], 0, 0, 0);
            acc[1][n] = __builtin_amdgcn_mfma_f32_16x16x32_bf16(ah1, bl, acc[1][n], 0, 0, 0);
            acc[1][n] = __builtin_amdgcn_mfma_f32_16x16x32_bf16(al1, bh, acc[1][n], 0, 0, 0);
            acc[1][n] = __builtin_amdgcn_mfma_f32_16x16x32_bf16(al1, bl, acc[1][n], 0, 0, 0);
        }
    }
    __syncthreads();  // all A reads done before in-place transposed stores

#pragma unroll
    for (int s = 0; s < 2; ++s) {
#pragma unroll
        for (int n = 0; n < 8; ++n) {
            const int col = n * 16 + l15;
            const unsigned rloc = wave * 32 + s * 16 + lg * 4;  // C rows rloc..rloc+3
            const unsigned grow = blkrow + rloc;
            const unsigned bm = grow >> 7;
            const unsigned rr = grow & 127;
            f32x4 v = acc[s][n];
            if (DODINV) {
                f32x4 d = *(const f32x4*)&DINVg[col * NN + rr];
                v.x *= d.x; v.y *= d.y; v.z *= d.z; v.w *= d.w;
            }
            *(f32x4*)&O[(size_t)bm * 16384 + (size_t)col * NN + rr] = v;
        }
    }
}

// Per (b,m): stage U[bm] in LDS, compute t = alpha_m*s2*(dlx*g0x+dly*g0y),
// overwrite slice in place (interior only; k_reduce guards pads).
__global__ __launch_bounds__(256) void k_tpass(const float* __restrict__ theta2,
                                               const float* __restrict__ alpha,
                                               const float* __restrict__ dlx,
                                               const float* __restrict__ dly,
                                               float* __restrict__ B1) {
    __shared__ float X[NN * NN];
    const int bm = blockIdx.x;
    const int b = bm >> 7, m = bm & 127;
    float* Ug = B1 + (size_t)bm * NN * NN;
    const int tid = threadIdx.x;
    for (int k = tid; k < NN * NN; k += 256) X[k] = Ug[k];
    __syncthreads();
    const float* th2 = theta2 + m * NN * NN;
    const float alm = alpha[m];
    const float* dlxb = dlx + b * NN * NN;
    const float* dlyb = dly + b * NN * NN;
    for (int k = tid; k < NN * NN; k += 256) {
        int r = k >> 7, c = k & 127;
        if (r < NI && c < NI) {
            int fi = (r + 1) * NN + (c + 1);
            float uxm = (r >= 1) ? X[k - NN] : 0.f;
            float uxp = X[k + NN];
            float uym = (c >= 1) ? X[k - 1] : 0.f;
            float uyp = X[k + 1];
            float g0x = 63.5f * (uxp - uxm);
            float g0y = 63.5f * (uyp - uym);
            float s2 = sigma_gamma(th2[fi]);
            Ug[k] = alm * s2 * (dlxb[fi] * g0x + dlyb[fi] * g0y);
        }
    }
}

// R2[b,r,c] = inva*S1a + sum_m t_all[b,m,r,c]  (pads -> 0)
__global__ __launch_bounds__(256) void k_reduce(const float* __restrict__ t_all,
                                                const float* __restrict__ inva,
                                                const float* __restrict__ S1a,
                                                float* __restrict__ R2) {
    int id = blockIdx.x * blockDim.x + threadIdx.x;
    if (id >= BB * NN * NN) return;
    int b = id >> 14;
    int k = id & 16383;
    int r = k >> 7, c = k & 127;
    float v = 0.f;
    if (r < NI && c < NI) {
        int fi = (r + 1) * NN + (c + 1);
        v = inva[b * NN * NN + fi] * S1a[fi];
        const float* tp = t_all + (size_t)b * MM_ * NN * NN + k;
        for (int m = 0; m < MM_; ++m) v += tp[(size_t)m * NN * NN];
    }
    R2[id] = v;
}

// out[b][x][y] = U2[b][x-1][y-1] on interior, 0 on boundary.
__global__ __launch_bounds__(256) void k_final(const float* __restrict__ U2,
                                               float* __restrict__ out) {
    int id = blockIdx.x * 256 + threadIdx.x;  // 131072
    int b = id >> 14, k = id & 16383, r = k >> 7, c = k & 127;
    float v = 0.f;
    if (r >= 1 && r <= 126 && c >= 1 && c <= 126)
        v = U2[b * 16384 + (r - 1) * NN + (c - 1)];
    out[id] = v;
}

extern "C" void kernel_launch(void* const* d_in, const int* in_sizes, int n_in,
                              void* d_out, int out_size, void* d_ws,
                              size_t ws_size, hipStream_t stream) {
    const float* a      = (const float*)d_in[0];
    const float* theta1 = (const float*)d_in[1];
    const float* theta2 = (const float*)d_in[2];
    const float* alpha  = (const float*)d_in[3];
    float* out = (float*)d_out;

    float* w = (float*)d_ws;
    float* DINV = w;                     // 16384
    float* inva = w + 16384;             // 131072
    float* dlx  = w + 147456;            // 131072
    float* dly  = w + 278528;            // 131072
    float* S1a  = w + 409600;            // 16384
    float* R2   = w + 425984;            // 131072
    float* T1   = w + 557056;            // 131072
    float* U2   = w + 688128;            // 131072
    unsigned short* Shi = (unsigned short*)(w + 819200);  // 16384 ushorts
    unsigned short* Slo = (unsigned short*)(w + 827392);  // 16384 ushorts
    float* B1   = w + 835584;            // 16777216 (1024 grids, in-place chain)

    k_prep<<<64, 256, 0, stream>>>(Shi, Slo, DINV);
    k_smooth<<<BB, 1024, 0, stream>>>(a, inva, dlx, dly);
    k_s1a<<<64, 256, 0, stream>>>(theta1, alpha, S1a);
    k_genR<<<8192, 256, 0, stream>>>(theta1, inva, B1);

    // stage 1: poisson over 1024 grids = 4 flat GEMMs, in place on B1
    k_gemm<false><<<512, 512, 0, stream>>>(B1, B1, Shi, Slo, DINV);
    k_gemm<true ><<<512, 512, 0, stream>>>(B1, B1, Shi, Slo, DINV);
    k_gemm<false><<<512, 512, 0, stream>>>(B1, B1, Shi, Slo, DINV);
    k_gemm<false><<<512, 512, 0, stream>>>(B1, B1, Shi, Slo, DINV);

    k_tpass<<<BB * MM_, 256, 0, stream>>>(theta2, alpha, dlx, dly, B1);
    k_reduce<<<512, 256, 0, stream>>>(B1, inva, S1a, R2);

    // stage 2: poisson over 8 grids (M = 1024 rows)
    k_gemm<false><<<4, 512, 0, stream>>>(R2, T1, Shi, Slo, DINV);
    k_gemm<true ><<<4, 512, 0, stream>>>(T1, T1, Shi, Slo, DINV);
    k_gemm<false><<<4, 512, 0, stream>>>(T1, T1, Shi, Slo, DINV);
    k_gemm<false><<<4, 512, 0, stream>>>(T1, U2, Shi, Slo, DINV);

    k_final<<<512, 256, 0, stream>>>(U2, out);
}

// Round 3
// 233.339 us; speedup vs baseline: 3.3563x; 1.5737x over previous
//
#include <hip/hip_runtime.h>
#include <math.h>

#ifndef M_PI
#define M_PI 3.14159265358979323846
#endif

typedef unsigned short u16;
typedef __attribute__((ext_vector_type(8))) short bf16x8;
typedef __attribute__((ext_vector_type(4))) float f32x4;

#define LDW 136  // ushort stride for LDS matrices (272B rows -> every octet 16B-aligned)

__device__ __forceinline__ float sigma_gamma(float r) {
    float s = 1.0f / (1.0f + __expf(r * (-1.0f / 0.15f)));
    return 0.4166666666666667f * s - 0.3333333333333333f;
}

// split f32 -> bf16 hi (truncate) + bf16 lo (RNE of residual); hi+lo ~ 2^-17 rel
__device__ __forceinline__ void split1(float x, u16& h, u16& l) {
    unsigned u = __float_as_uint(x);
    unsigned hb = u & 0xffff0000u;
    h = (u16)(hb >> 16);
    float d = x - __uint_as_float(hb);
    unsigned ud = __float_as_uint(d);
    l = (u16)((ud + 0x7fffu + ((ud >> 16) & 1u)) >> 16);
}

// Precompute: DST sine matrix S (bf16 hi/lo), DCT-II basis Q and its transpose
// (bf16 hi/lo), Poisson spectral inverse DINV, smoother spectral filter G.
__global__ __launch_bounds__(256) void k_prep(
    u16* __restrict__ Shi, u16* __restrict__ Slo,
    u16* __restrict__ Qhi, u16* __restrict__ Qlo,
    u16* __restrict__ QThi, u16* __restrict__ QTlo,
    float* __restrict__ DINV, float* __restrict__ G) {
    int id = blockIdx.x * 256 + threadIdx.x;
    if (id >= 16384) return;
    int r = id >> 7, c = id & 127;
    u16 h, l;
    // S: 126x126 valid, zero-padded to 128
    float s = 0.f, di = 0.f;
    if (r < 126 && c < 126) {
        int prod = ((r + 1) * (c + 1)) % 254;
        s = (float)sin((double)prod * (M_PI / 127.0));
        double sr = sin((double)(r + 1) * (M_PI / 254.0));
        double sc = sin((double)(c + 1) * (M_PI / 254.0));
        di = (float)(16.0 / (64516.0 * 16129.0 * 4.0 * (sr * sr + sc * sc)));
    }
    split1(s, h, l); Shi[id] = h; Slo[id] = l;
    DINV[id] = di;
    // Q[i=r][k=c] = n_c cos(pi c (2r+1)/256)  (orthonormal DCT-II basis)
    double nc = (c == 0) ? sqrt(1.0 / 128.0) : sqrt(2.0 / 128.0);
    float q = (float)(nc * cos(M_PI * (double)c * (double)(2 * r + 1) / 256.0));
    split1(q, h, l); Qhi[id] = h; Qlo[id] = l;
    // QT[i=r][j=c] = Q[c][r]
    double nr = (r == 0) ? sqrt(1.0 / 128.0) : sqrt(2.0 / 128.0);
    float qt = (float)(nr * cos(M_PI * (double)r * (double)(2 * c + 1) / 256.0));
    split1(qt, h, l); QThi[id] = h; QTlo[id] = l;
    // G[k=r][l=c] = (1 + DT*ETA/H^2 * (lam_r + lam_c))^34
    double lr = 2.0 * cos(M_PI * (double)r / 128.0) - 2.0;
    double lc = 2.0 * cos(M_PI * (double)c / 128.0) - 2.0;
    G[id] = (float)pow(1.0 + 0.03 * 1e-4 * 16129.0 * (lr + lc), 34.0);
}

// S1a[x,y] = sum_m alpha_m * sigma(theta1[m,x,y])
__global__ __launch_bounds__(256) void k_s1a(const float* __restrict__ theta1,
                                             const float* __restrict__ alpha,
                                             float* __restrict__ S1a) {
    int id = blockIdx.x * 256 + threadIdx.x;
    if (id >= 16384) return;
    float acc = 0.f;
    for (int m = 0; m < 128; ++m)
        acc += alpha[m] * sigma_gamma(theta1[m * 16384 + id]);
    S1a[id] = acc;
}

// One in-LDS matmul pass: O = (X * W)^T, X as bf16 hi/lo in LDS, W staged in
// LDS as W_lds[col][k] = W[k][col]. DOD: elementwise D on the stored array.
// LAST: store f32 into UF (aliases Xhi/Xlo) instead of split bf16.
template <bool DOD, bool LAST>
__device__ __forceinline__ void mm_pass(u16* Xhi, u16* Xlo, float* UF,
                                        const u16* WH, const u16* WL,
                                        const float* Dg,
                                        int wave, int l15, int lg) {
    bf16x8 ah[4], al[4];
    {
        const u16* xh = Xhi + (wave * 16 + l15) * LDW + lg * 8;
        const u16* xl = Xlo + (wave * 16 + l15) * LDW + lg * 8;
#pragma unroll
        for (int kb = 0; kb < 4; ++kb) {
            ah[kb] = *(const bf16x8*)(xh + kb * 32);
            al[kb] = *(const bf16x8*)(xl + kb * 32);
        }
    }
    __syncthreads();  // all waves' A-reads done before any transposed write
    f32x4 acc[8];
#pragma unroll
    for (int n = 0; n < 8; ++n) acc[n] = f32x4{0.f, 0.f, 0.f, 0.f};
#pragma unroll
    for (int n = 0; n < 8; ++n) {
        const u16* wh = WH + (n * 16 + l15) * LDW + lg * 8;
        const u16* wl = WL + (n * 16 + l15) * LDW + lg * 8;
#pragma unroll
        for (int kb = 0; kb < 4; ++kb) {
            bf16x8 bh = *(const bf16x8*)(wh + kb * 32);
            bf16x8 bl = *(const bf16x8*)(wl + kb * 32);
            acc[n] = __builtin_amdgcn_mfma_f32_16x16x32_bf16(ah[kb], bh, acc[n], 0, 0, 0);
            acc[n] = __builtin_amdgcn_mfma_f32_16x16x32_bf16(al[kb], bh, acc[n], 0, 0, 0);
            acc[n] = __builtin_amdgcn_mfma_f32_16x16x32_bf16(ah[kb], bl, acc[n], 0, 0, 0);
            acc[n] = __builtin_amdgcn_mfma_f32_16x16x32_bf16(al[kb], bl, acc[n], 0, 0, 0);
        }
    }
    const int row0 = wave * 16 + lg * 4;
#pragma unroll
    for (int n = 0; n < 8; ++n) {
        const int col = n * 16 + l15;
        f32x4 v = acc[n];
        if (DOD) {
            f32x4 d = *(const f32x4*)(Dg + col * 128 + row0);
            v.x *= d.x; v.y *= d.y; v.z *= d.z; v.w *= d.w;
        }
        if (LAST) {
            *(f32x4*)(UF + col * LDW + row0) = v;
        } else {
            u16 h0, h1, h2, h3, l0, l1, l2, l3;
            split1(v.x, h0, l0); split1(v.y, h1, l1);
            split1(v.z, h2, l2); split1(v.w, h3, l3);
            uint2 uh, ul;
            uh.x = (unsigned)h0 | ((unsigned)h1 << 16);
            uh.y = (unsigned)h2 | ((unsigned)h3 << 16);
            ul.x = (unsigned)l0 | ((unsigned)l1 << 16);
            ul.y = (unsigned)l2 | ((unsigned)l3 << 16);
            *(uint2*)(Xhi + col * LDW + row0) = uh;
            *(uint2*)(Xlo + col * LDW + row0) = ul;
        }
    }
    __syncthreads();
}

// MODE 0: smooth (8 blocks). X=a; P1/2 with QT-layout, G, restage, P3/4 with
//         Q-layout -> a_eps; epilogue: inva, log-gradient dlx/dly.
// MODE 1: stage-1 Poisson (256 blocks = 8b x 32 groups of 4 m). Per m: X from
//         sigma(theta1)*inva, 4 S-passes + DINV -> p0; t-term accumulated in
//         registers across 4 m; partial written to Pp[block].
// MODE 2: stage-2 Poisson (8 blocks). X=R2 -> phi; write d_out with zero bc.
template <int MODE>
__global__ __launch_bounds__(512) void k_mega(
    const u16* __restrict__ WHg, const u16* __restrict__ WLg,
    const u16* __restrict__ WHg2, const u16* __restrict__ WLg2,
    const float* __restrict__ Dmat,
    const float* __restrict__ src, const float* __restrict__ aux,
    const float* __restrict__ th2, const float* __restrict__ alpha,
    const float* __restrict__ dlxc, const float* __restrict__ dlyc,
    float* __restrict__ o1, float* __restrict__ o2, float* __restrict__ o3) {
    __shared__ __align__(16) char SM[139264];
    u16* Xhi = (u16*)SM;                   // 34816 B
    u16* Xlo = (u16*)(SM + 34816);         // 34816 B
    float* UF = (float*)SM;                // alias Xhi+Xlo (f32 final pass)
    u16* WH = (u16*)(SM + 69632);          // 34816 B
    u16* WL = (u16*)(SM + 104448);         // 34816 B
    float* LG = (float*)(SM + 69632);      // alias W region (MODE 0 epilogue)

    const int tid = threadIdx.x;
    const int wave = tid >> 6, lane = tid & 63;
    const int l15 = lane & 15, lg = lane >> 4;

    // stage W (pass-1/2 matrix)
    for (int idx = tid; idx < 16384; idx += 512) {
        int i = idx >> 7, j = idx & 127;
        WH[i * LDW + j] = WHg[idx];
        WL[i * LDW + j] = WLg[idx];
    }

    int b, m0;
    if (MODE == 1) { b = blockIdx.x >> 5; m0 = (blockIdx.x & 31) * 4; }
    else { b = blockIdx.x; m0 = 0; }

    float tac[32];
    if (MODE == 1) {
#pragma unroll
        for (int p = 0; p < 32; ++p) tac[p] = 0.f;
    }

    const int MLOOP = (MODE == 1) ? 4 : 1;
    for (int mi = 0; mi < MLOOP; ++mi) {
        // ---- init X (bf16 hi/lo) ----
        for (int idx = tid; idx < 16384; idx += 512) {
            int i = idx >> 7, j = idx & 127;
            float v;
            if (MODE == 1) {
                v = 0.f;
                if (i < 126 && j < 126) {
                    int fi = (i + 1) * 128 + (j + 1);
                    v = sigma_gamma(src[(size_t)(m0 + mi) * 16384 + fi]) *
                        aux[b * 16384 + fi];
                }
            } else {
                v = src[b * 16384 + idx];
            }
            u16 h, l; split1(v, h, l);
            Xhi[i * LDW + j] = h; Xlo[i * LDW + j] = l;
        }
        __syncthreads();

        mm_pass<false, false>(Xhi, Xlo, UF, WH, WL, nullptr, wave, l15, lg);
        mm_pass<true,  false>(Xhi, Xlo, UF, WH, WL, Dmat,    wave, l15, lg);
        if (MODE == 0) {  // restage W = Q-layout for passes 3/4
            for (int idx = tid; idx < 16384; idx += 512) {
                int i = idx >> 7, j = idx & 127;
                WH[i * LDW + j] = WHg2[idx];
                WL[i * LDW + j] = WLg2[idx];
            }
            __syncthreads();
        }
        mm_pass<false, false>(Xhi, Xlo, UF, WH, WL, nullptr, wave, l15, lg);
        mm_pass<false, true >(Xhi, Xlo, UF, WH, WL, nullptr, wave, l15, lg);
        // UF now holds the solved field (f32), pads exactly zero for MODE 1/2.

        if (MODE == 0) {
            for (int idx = tid; idx < 16384; idx += 512) {
                int i = idx >> 7, j = idx & 127;
                float ae = UF[i * LDW + j];
                o1[b * 16384 + idx] = 1.0f / ae;            // inva
                LG[i * LDW + j] = logf(fmaxf(ae, 1e-9f));
            }
            __syncthreads();
            for (int idx = tid; idx < 16384; idx += 512) {
                int i = idx >> 7, j = idx & 127;
                if (i >= 1 && i <= 126 && j >= 1 && j <= 126) {
                    o2[b * 16384 + idx] = 63.5f * (LG[(i + 1) * LDW + j] - LG[(i - 1) * LDW + j]);
                    o3[b * 16384 + idx] = 63.5f * (LG[i * LDW + j + 1] - LG[i * LDW + j - 1]);
                }
            }
        } else if (MODE == 1) {
            const float alm = alpha[m0 + mi];
            int p = 0;
            for (int idx = tid; idx < 16384; idx += 512, ++p) {
                int i = idx >> 7, j = idx & 127;
                if (i < 126 && j < 126) {
                    int fi = (i + 1) * 128 + (j + 1);
                    float uxp = UF[(i + 1) * LDW + j];            // row 126 == 0
                    float uxm = (i > 0) ? UF[(i - 1) * LDW + j] : 0.f;
                    float uyp = UF[i * LDW + j + 1];
                    float uym = (j > 0) ? UF[i * LDW + j - 1] : 0.f;
                    float g0x = 63.5f * (uxp - uxm);
                    float g0y = 63.5f * (uyp - uym);
                    float s2 = sigma_gamma(th2[(size_t)(m0 + mi) * 16384 + fi]);
                    tac[p] += alm * s2 *
                              (dlxc[b * 16384 + fi] * g0x + dlyc[b * 16384 + fi] * g0y);
                }
            }
            __syncthreads();  // UF reads done before next m's init overwrites
        } else {
            for (int idx = tid; idx < 16384; idx += 512) {
                int r = idx >> 7, c = idx & 127;
                float v = 0.f;
                if (r >= 1 && r <= 126 && c >= 1 && c <= 126)
                    v = UF[(r - 1) * LDW + (c - 1)];
                o1[b * 16384 + idx] = v;
            }
        }
    }
    if (MODE == 1) {
        int p = 0;
        for (int idx = tid; idx < 16384; idx += 512, ++p)
            o1[(size_t)blockIdx.x * 16384 + idx] = tac[p];
    }
}

// R2[b] = inva*S1a (interior) + sum over 32 partials; pads -> 0.
__global__ __launch_bounds__(256) void k_reduce(const float* __restrict__ Pp,
                                                const float* __restrict__ inva,
                                                const float* __restrict__ S1a,
                                                float* __restrict__ R2) {
    int id = blockIdx.x * 256 + threadIdx.x;  // 131072
    int b = id >> 14, k = id & 16383;
    int r = k >> 7, c = k & 127;
    float v = 0.f;
    if (r < 126 && c < 126) {
        int fi = (r + 1) * 128 + (c + 1);
        v = inva[b * 16384 + fi] * S1a[fi];
        const float* tp = Pp + (size_t)(b * 32) * 16384 + k;
#pragma unroll 8
        for (int g = 0; g < 32; ++g) v += tp[(size_t)g * 16384];
    }
    R2[id] = v;
}

extern "C" void kernel_launch(void* const* d_in, const int* in_sizes, int n_in,
                              void* d_out, int out_size, void* d_ws,
                              size_t ws_size, hipStream_t stream) {
    const float* a      = (const float*)d_in[0];
    const float* theta1 = (const float*)d_in[1];
    const float* theta2 = (const float*)d_in[2];
    const float* alpha  = (const float*)d_in[3];
    float* out = (float*)d_out;

    float* w = (float*)d_ws;
    float* DINV = w;                       // 16384
    float* G    = w + 16384;               // 16384
    float* inva = w + 32768;               // 131072
    float* dlx  = w + 163840;              // 131072
    float* dly  = w + 294912;              // 131072
    float* S1a  = w + 425984;              // 16384
    float* R2   = w + 442368;              // 131072
    float* Pp   = w + 573440;              // 4194304 (256 partial slices)
    u16* Shi  = (u16*)(w + 4767744);       // 16384 u16 each
    u16* Slo  = (u16*)(w + 4775936);
    u16* Qhi  = (u16*)(w + 4784128);
    u16* Qlo  = (u16*)(w + 4792320);
    u16* QThi = (u16*)(w + 4800512);
    u16* QTlo = (u16*)(w + 4808704);

    k_prep<<<64, 256, 0, stream>>>(Shi, Slo, Qhi, Qlo, QThi, QTlo, DINV, G);

    // spectral smooth -> inva, dlx, dly
    k_mega<0><<<8, 512, 0, stream>>>(QThi, QTlo, Qhi, Qlo, G, a, nullptr,
                                     nullptr, nullptr, nullptr, nullptr,
                                     inva, dlx, dly);

    k_s1a<<<64, 256, 0, stream>>>(theta1, alpha, S1a);

    // stage-1: 1024 Poisson solves fully in LDS, t-term partials out
    k_mega<1><<<256, 512, 0, stream>>>(Shi, Slo, nullptr, nullptr, DINV,
                                       theta1, inva, theta2, alpha, dlx, dly,
                                       Pp, nullptr, nullptr);

    k_reduce<<<512, 256, 0, stream>>>(Pp, inva, S1a, R2);

    // stage-2: 8 Poisson solves, write output with zero boundary
    k_mega<2><<<8, 512, 0, stream>>>(Shi, Slo, nullptr, nullptr, DINV,
                                     R2, nullptr, nullptr, nullptr, nullptr,
                                     nullptr, out, nullptr, nullptr);
}

// Round 4
// 155.559 us; speedup vs baseline: 5.0345x; 1.5000x over previous
//
#include <hip/hip_runtime.h>
#include <math.h>

#ifndef M_PI
#define M_PI 3.14159265358979323846
#endif

typedef unsigned short u16;
typedef __attribute__((ext_vector_type(8))) short bf16x8;
typedef __attribute__((ext_vector_type(4))) float f32x4;
typedef __attribute__((ext_vector_type(16))) float f32x16;

#define LDW 136   // u16 stride for LDS bf16 matrices (272B rows, octets 16B-aligned)
#define LDWF 132  // f32 stride for LDS f32 matrices (528B rows, 16B-aligned)

__device__ __forceinline__ float sigma_gamma(float r) {
    float s = 1.0f / (1.0f + __expf(r * (-1.0f / 0.15f)));
    return 0.4166666666666667f * s - 0.3333333333333333f;
}

// split f32 -> bf16 hi (truncate) + bf16 lo (RNE of residual); hi+lo ~ 2^-17 rel
__device__ __forceinline__ void split1(float x, u16& h, u16& l) {
    unsigned u = __float_as_uint(x);
    unsigned hb = u & 0xffff0000u;
    h = (u16)(hb >> 16);
    float d = x - __uint_as_float(hb);
    unsigned ud = __float_as_uint(d);
    l = (u16)((ud + 0x7fffu + ((ud >> 16) & 1u)) >> 16);
}

__global__ __launch_bounds__(256) void k_prep(
    u16* __restrict__ Shi, u16* __restrict__ Slo,
    u16* __restrict__ Qhi, u16* __restrict__ Qlo,
    u16* __restrict__ QThi, u16* __restrict__ QTlo,
    float* __restrict__ DINV, float* __restrict__ G) {
    int id = blockIdx.x * 256 + threadIdx.x;
    if (id >= 16384) return;
    int r = id >> 7, c = id & 127;
    u16 h, l;
    float s = 0.f, di = 0.f;
    if (r < 126 && c < 126) {
        int prod = ((r + 1) * (c + 1)) % 254;
        s = (float)sin((double)prod * (M_PI / 127.0));
        double sr = sin((double)(r + 1) * (M_PI / 254.0));
        double sc = sin((double)(c + 1) * (M_PI / 254.0));
        di = (float)(16.0 / (64516.0 * 16129.0 * 4.0 * (sr * sr + sc * sc)));
    }
    split1(s, h, l); Shi[id] = h; Slo[id] = l;
    DINV[id] = di;
    double nc = (c == 0) ? sqrt(1.0 / 128.0) : sqrt(2.0 / 128.0);
    float q = (float)(nc * cos(M_PI * (double)c * (double)(2 * r + 1) / 256.0));
    split1(q, h, l); Qhi[id] = h; Qlo[id] = l;
    double nr = (r == 0) ? sqrt(1.0 / 128.0) : sqrt(2.0 / 128.0);
    float qt = (float)(nr * cos(M_PI * (double)r * (double)(2 * c + 1) / 256.0));
    split1(qt, h, l); QThi[id] = h; QTlo[id] = l;
    double lr = 2.0 * cos(M_PI * (double)r / 128.0) - 2.0;
    double lc = 2.0 * cos(M_PI * (double)c / 128.0) - 2.0;
    G[id] = (float)pow(1.0 + 0.03 * 1e-4 * 16129.0 * (lr + lc), 34.0);
}

// One matmul pass with 32x32x16 MFMA: C = X * W_lds^T, stored transposed.
// Wave (rt,ct) computes tile rows rt*32..+31, cols ct*32..+31. 3-term hi/lo.
template <bool DOD, bool LAST>
__device__ __forceinline__ void mm_pass32(u16* Xhi, u16* Xlo, float* UF,
                                          const u16* WH, const u16* WL,
                                          const float* Dg, int rt, int ct,
                                          int l31, int hb) {
    f32x16 acc;
#pragma unroll
    for (int i = 0; i < 16; ++i) acc[i] = 0.f;
    const u16* xh = Xhi + (rt * 32 + l31) * LDW + hb * 8;
    const u16* xl = Xlo + (rt * 32 + l31) * LDW + hb * 8;
    const u16* wh = WH + (ct * 32 + l31) * LDW + hb * 8;
    const u16* wl = WL + (ct * 32 + l31) * LDW + hb * 8;
#pragma unroll
    for (int s = 0; s < 8; ++s) {
        bf16x8 ah = *(const bf16x8*)(xh + s * 16);
        bf16x8 al = *(const bf16x8*)(xl + s * 16);
        bf16x8 bh = *(const bf16x8*)(wh + s * 16);
        bf16x8 bl = *(const bf16x8*)(wl + s * 16);
        acc = __builtin_amdgcn_mfma_f32_32x32x16_bf16(ah, bh, acc, 0, 0, 0);
        acc = __builtin_amdgcn_mfma_f32_32x32x16_bf16(al, bh, acc, 0, 0, 0);
        acc = __builtin_amdgcn_mfma_f32_32x32x16_bf16(ah, bl, acc, 0, 0, 0);
    }
    __syncthreads();  // all reads of X done before transposed overwrite
    const int colX = ct * 32 + l31;
#pragma unroll
    for (int g = 0; g < 4; ++g) {
        const int rbase = rt * 32 + 8 * g + 4 * hb;
        float v0 = acc[4 * g], v1 = acc[4 * g + 1];
        float v2 = acc[4 * g + 2], v3 = acc[4 * g + 3];
        if (DOD) {
            f32x4 d = *(const f32x4*)(Dg + colX * 128 + rbase);
            v0 *= d[0]; v1 *= d[1]; v2 *= d[2]; v3 *= d[3];
        }
        if (LAST) {
            f32x4 o = {v0, v1, v2, v3};
            *(f32x4*)(UF + colX * LDWF + rbase) = o;
        } else {
            u16 h0, l0, h1, l1, h2, l2, h3, l3;
            split1(v0, h0, l0); split1(v1, h1, l1);
            split1(v2, h2, l2); split1(v3, h3, l3);
            uint2 uh, ul;
            uh.x = (unsigned)h0 | ((unsigned)h1 << 16);
            uh.y = (unsigned)h2 | ((unsigned)h3 << 16);
            ul.x = (unsigned)l0 | ((unsigned)l1 << 16);
            ul.y = (unsigned)l2 | ((unsigned)l3 << 16);
            *(uint2*)(Xhi + colX * LDW + rbase) = uh;
            *(uint2*)(Xlo + colX * LDW + rbase) = ul;
        }
    }
    __syncthreads();
}

// MODE 0: blocks 0..7 spectral smooth (inva, dlx, dly); blocks 8..135 S1a.
// MODE 1: 256 blocks (8b x 32 groups x 4m): Poisson + t-term partials -> Pp.
// MODE 2: 8 blocks: Poisson on reduced rhs -> d_out with zero boundary.
template <int MODE>
__global__ __launch_bounds__(1024, 4) void k_mega(
    const u16* __restrict__ WHg, const u16* __restrict__ WLg,
    const u16* __restrict__ WHg2, const u16* __restrict__ WLg2,
    const float* __restrict__ Dmat,
    const float* __restrict__ src, const float* __restrict__ aux,
    const float* __restrict__ th2, const float* __restrict__ alpha,
    const float* __restrict__ dlxc, const float* __restrict__ dlyc,
    float* __restrict__ o1, float* __restrict__ o2, float* __restrict__ o3,
    float* __restrict__ o4) {
    __shared__ __align__(16) char SM[139264];
    u16* Xhi = (u16*)SM;                 // 34816 B
    u16* Xlo = (u16*)(SM + 34816);       // 34816 B
    float* UF = (float*)SM;              // alias (f32, stride LDWF, final pass)
    u16* WH = (u16*)(SM + 69632);
    u16* WL = (u16*)(SM + 104448);
    float* LG = (float*)(SM + 69632);    // alias W region (MODE0 epilogue)

    const int tid = threadIdx.x;

    if (MODE == 0 && blockIdx.x >= 8) {  // ---- S1a blocks ----
        float* red = (float*)SM;
        const int px0 = (blockIdx.x - 8) * 128;
        const int pl = tid & 127, mg = tid >> 7;
        float acc = 0.f;
        for (int i = 0; i < 16; ++i) {
            int m = mg * 16 + i;
            acc += alpha[m] * sigma_gamma(th2[m * 16384 + px0 + pl]);
        }
        red[tid] = acc;
        __syncthreads();
        if (tid < 128) {
            float sum = 0.f;
#pragma unroll
            for (int g = 0; g < 8; ++g) sum += red[tid + g * 128];
            o4[px0 + tid] = sum;
        }
        return;
    }

    const int wave = tid >> 6, lane = tid & 63;
    const int rt = wave >> 2, ct = wave & 3;
    const int l31 = lane & 31, hb = lane >> 5;

    int b, m0;
    if (MODE == 1) { b = blockIdx.x >> 5; m0 = (blockIdx.x & 31) * 4; }
    else { b = blockIdx.x; m0 = 0; }

    // stage W (2 b128 chunks per thread per matrix)
#pragma unroll
    for (int p = 0; p < 2; ++p) {
        int ch = tid + p * 1024;
        int r = ch >> 4, j0 = (ch & 15) * 8;
        *(uint4*)&WH[r * LDW + j0] = *(const uint4*)(WHg + r * 128 + j0);
        *(uint4*)&WL[r * LDW + j0] = *(const uint4*)(WLg + r * 128 + j0);
    }

    float tac[16];
    if (MODE == 1) {
#pragma unroll
        for (int i = 0; i < 16; ++i) tac[i] = 0.f;
    }

    const int ML = (MODE == 1) ? 4 : 1;
    for (int mi = 0; mi < ML; ++mi) {
        // ---- init X ----
#pragma unroll
        for (int p = 0; p < 2; ++p) {
            int ch = tid + p * 1024;
            int row = ch >> 4, c0 = (ch & 15) * 8;
            float v[8];
            if (MODE == 1) {
                const float* t1 = src + (size_t)(m0 + mi) * 16384;
                const float* iv = aux + b * 16384;
                if (row < 126) {
                    int base = (row + 1) * 128 + 1;
#pragma unroll
                    for (int j = 0; j < 8; ++j) {
                        int c = c0 + j;
                        v[j] = (c < 126)
                                   ? sigma_gamma(t1[base + c]) * iv[base + c]
                                   : 0.f;
                    }
                } else {
#pragma unroll
                    for (int j = 0; j < 8; ++j) v[j] = 0.f;
                }
            } else {
                f32x4 p0 = *(const f32x4*)(src + b * 16384 + ch * 8);
                f32x4 p1 = *(const f32x4*)(src + b * 16384 + ch * 8 + 4);
#pragma unroll
                for (int j = 0; j < 4; ++j) { v[j] = p0[j]; v[j + 4] = p1[j]; }
            }
            unsigned hw[4], lw[4];
#pragma unroll
            for (int k = 0; k < 4; ++k) {
                u16 ha, la, hbb, lb;
                split1(v[2 * k], ha, la);
                split1(v[2 * k + 1], hbb, lb);
                hw[k] = (unsigned)ha | ((unsigned)hbb << 16);
                lw[k] = (unsigned)la | ((unsigned)lb << 16);
            }
            *(uint4*)&Xhi[row * LDW + c0] = make_uint4(hw[0], hw[1], hw[2], hw[3]);
            *(uint4*)&Xlo[row * LDW + c0] = make_uint4(lw[0], lw[1], lw[2], lw[3]);
        }
        __syncthreads();

        mm_pass32<false, false>(Xhi, Xlo, UF, WH, WL, nullptr, rt, ct, l31, hb);
        mm_pass32<true, false>(Xhi, Xlo, UF, WH, WL, Dmat, rt, ct, l31, hb);
        if (MODE == 0) {  // restage W = Q for passes 3/4
#pragma unroll
            for (int p = 0; p < 2; ++p) {
                int ch = tid + p * 1024;
                int r = ch >> 4, j0 = (ch & 15) * 8;
                *(uint4*)&WH[r * LDW + j0] = *(const uint4*)(WHg2 + r * 128 + j0);
                *(uint4*)&WL[r * LDW + j0] = *(const uint4*)(WLg2 + r * 128 + j0);
            }
            __syncthreads();
        }
        mm_pass32<false, false>(Xhi, Xlo, UF, WH, WL, nullptr, rt, ct, l31, hb);
        mm_pass32<false, true>(Xhi, Xlo, UF, WH, WL, nullptr, rt, ct, l31, hb);
        // UF = solved field (f32, stride LDWF)

        if (MODE == 0) {
#pragma unroll
            for (int p = 0; p < 2; ++p) {
                int ch = tid + p * 1024;
                int row = ch >> 4, c0 = (ch & 15) * 8;
                f32x4 a0 = *(const f32x4*)(UF + row * LDWF + c0);
                f32x4 a1 = *(const f32x4*)(UF + row * LDWF + c0 + 4);
                f32x4 i0, i1, g0, g1;
#pragma unroll
                for (int j = 0; j < 4; ++j) {
                    i0[j] = 1.0f / a0[j]; i1[j] = 1.0f / a1[j];
                    g0[j] = logf(fmaxf(a0[j], 1e-9f));
                    g1[j] = logf(fmaxf(a1[j], 1e-9f));
                }
                *(f32x4*)(o1 + b * 16384 + ch * 8) = i0;
                *(f32x4*)(o1 + b * 16384 + ch * 8 + 4) = i1;
                *(f32x4*)(LG + row * LDWF + c0) = g0;
                *(f32x4*)(LG + row * LDWF + c0 + 4) = g1;
            }
            __syncthreads();
#pragma unroll
            for (int p = 0; p < 2; ++p) {
                int ch = tid + p * 1024;
                int i = ch >> 4, c0 = (ch & 15) * 8;
                if (i < 1 || i > 126) continue;
                f32x4 up0 = *(const f32x4*)(LG + (i + 1) * LDWF + c0);
                f32x4 up1 = *(const f32x4*)(LG + (i + 1) * LDWF + c0 + 4);
                f32x4 um0 = *(const f32x4*)(LG + (i - 1) * LDWF + c0);
                f32x4 um1 = *(const f32x4*)(LG + (i - 1) * LDWF + c0 + 4);
                float win[13];
                win[0] = (c0 > 0) ? LG[i * LDWF + c0 - 1] : 0.f;
                f32x4 va = *(const f32x4*)(LG + i * LDWF + c0);
                f32x4 vb = *(const f32x4*)(LG + i * LDWF + c0 + 4);
                f32x4 vc = *(const f32x4*)(LG + i * LDWF + c0 + 8);
#pragma unroll
                for (int j = 0; j < 4; ++j) {
                    win[1 + j] = va[j]; win[5 + j] = vb[j]; win[9 + j] = vc[j];
                }
#pragma unroll
                for (int e = 0; e < 8; ++e) {
                    int j = c0 + e;
                    if (j < 1 || j > 126) continue;
                    float upv = (e < 4) ? up0[e] : up1[e - 4];
                    float umv = (e < 4) ? um0[e] : um1[e - 4];
                    o2[b * 16384 + i * 128 + j] = 63.5f * (upv - umv);
                    o3[b * 16384 + i * 128 + j] = 63.5f * (win[e + 2] - win[e]);
                }
            }
        } else if (MODE == 1) {
            const float* t2 = th2 + (size_t)(m0 + mi) * 16384;
            const float alm = alpha[m0 + mi];
            const float* dxb = dlxc + b * 16384;
            const float* dyb = dlyc + b * 16384;
#pragma unroll
            for (int p = 0; p < 2; ++p) {
                int ch = tid + p * 1024;
                int i = ch >> 4, c0 = (ch & 15) * 8;
                if (i >= 126) continue;
                f32x4 up0 = *(const f32x4*)(UF + (i + 1) * LDWF + c0);
                f32x4 up1 = *(const f32x4*)(UF + (i + 1) * LDWF + c0 + 4);
                f32x4 um0, um1;
                if (i > 0) {
                    um0 = *(const f32x4*)(UF + (i - 1) * LDWF + c0);
                    um1 = *(const f32x4*)(UF + (i - 1) * LDWF + c0 + 4);
                } else {
                    um0 = f32x4{0.f, 0.f, 0.f, 0.f}; um1 = um0;
                }
                float win[13];
                win[0] = (c0 > 0) ? UF[i * LDWF + c0 - 1] : 0.f;
                f32x4 va = *(const f32x4*)(UF + i * LDWF + c0);
                f32x4 vb = *(const f32x4*)(UF + i * LDWF + c0 + 4);
                f32x4 vc = *(const f32x4*)(UF + i * LDWF + c0 + 8);
#pragma unroll
                for (int j = 0; j < 4; ++j) {
                    win[1 + j] = va[j]; win[5 + j] = vb[j]; win[9 + j] = vc[j];
                }
#pragma unroll
                for (int e = 0; e < 8; ++e) {
                    int j = c0 + e;
                    if (j >= 126) continue;
                    int fi = (i + 1) * 128 + j + 1;
                    float upv = (e < 4) ? up0[e] : up1[e - 4];
                    float umv = (e < 4) ? um0[e] : um1[e - 4];
                    float g0x = 63.5f * (upv - umv);
                    float g0y = 63.5f * (win[e + 2] - win[e]);
                    float s2 = sigma_gamma(t2[fi]);
                    tac[p * 8 + e] += alm * s2 * (dxb[fi] * g0x + dyb[fi] * g0y);
                }
            }
            __syncthreads();  // UF reads done before next m's init overwrites
        } else {
#pragma unroll
            for (int p = 0; p < 2; ++p) {
                int ch = tid + p * 1024;
                int r = ch >> 4, c0 = (ch & 15) * 8;
#pragma unroll
                for (int e = 0; e < 8; ++e) {
                    int c = c0 + e;
                    float v = 0.f;
                    if (r >= 1 && r <= 126 && c >= 1 && c <= 126)
                        v = UF[(r - 1) * LDWF + (c - 1)];
                    o1[b * 16384 + r * 128 + c] = v;
                }
            }
        }
    }
    if (MODE == 1) {
#pragma unroll
        for (int p = 0; p < 2; ++p) {
            int ch = tid + p * 1024;
            f32x4 w0 = {tac[p * 8], tac[p * 8 + 1], tac[p * 8 + 2], tac[p * 8 + 3]};
            f32x4 w1 = {tac[p * 8 + 4], tac[p * 8 + 5], tac[p * 8 + 6], tac[p * 8 + 7]};
            *(f32x4*)(o1 + (size_t)blockIdx.x * 16384 + ch * 8) = w0;
            *(f32x4*)(o1 + (size_t)blockIdx.x * 16384 + ch * 8 + 4) = w1;
        }
    }
}

// R2[b] = inva*S1a (interior) + sum over 32 partials; pads -> 0.
__global__ __launch_bounds__(256) void k_reduce(const float* __restrict__ Pp,
                                                const float* __restrict__ inva,
                                                const float* __restrict__ S1a,
                                                float* __restrict__ R2) {
    int id = blockIdx.x * 256 + threadIdx.x;  // 131072
    int b = id >> 14, k = id & 16383;
    int r = k >> 7, c = k & 127;
    float v = 0.f;
    if (r < 126 && c < 126) {
        int fi = (r + 1) * 128 + (c + 1);
        v = inva[b * 16384 + fi] * S1a[fi];
        const float* tp = Pp + (size_t)(b * 32) * 16384 + k;
#pragma unroll 8
        for (int g = 0; g < 32; ++g) v += tp[(size_t)g * 16384];
    }
    R2[id] = v;
}

extern "C" void kernel_launch(void* const* d_in, const int* in_sizes, int n_in,
                              void* d_out, int out_size, void* d_ws,
                              size_t ws_size, hipStream_t stream) {
    const float* a      = (const float*)d_in[0];
    const float* theta1 = (const float*)d_in[1];
    const float* theta2 = (const float*)d_in[2];
    const float* alpha  = (const float*)d_in[3];
    float* out = (float*)d_out;

    float* w = (float*)d_ws;
    float* DINV = w;                       // 16384
    float* G    = w + 16384;               // 16384
    float* inva = w + 32768;               // 131072
    float* dlx  = w + 163840;              // 131072
    float* dly  = w + 294912;              // 131072
    float* S1a  = w + 425984;              // 16384
    float* R2   = w + 442368;              // 131072
    float* Pp   = w + 573440;              // 4194304 (256 partial slices)
    u16* Shi  = (u16*)(w + 4767744);
    u16* Slo  = (u16*)(w + 4775936);
    u16* Qhi  = (u16*)(w + 4784128);
    u16* Qlo  = (u16*)(w + 4792320);
    u16* QThi = (u16*)(w + 4800512);
    u16* QTlo = (u16*)(w + 4808704);

    k_prep<<<64, 256, 0, stream>>>(Shi, Slo, Qhi, Qlo, QThi, QTlo, DINV, G);

    // blocks 0-7: spectral smooth -> inva,dlx,dly; blocks 8-135: S1a
    k_mega<0><<<136, 1024, 0, stream>>>(QThi, QTlo, Qhi, Qlo, G, a, nullptr,
                                        theta1, alpha, nullptr, nullptr,
                                        inva, dlx, dly, S1a);

    // stage-1: 1024 Poisson solves fully in LDS, t-term partials -> Pp
    k_mega<1><<<256, 1024, 0, stream>>>(Shi, Slo, nullptr, nullptr, DINV,
                                        theta1, inva, theta2, alpha, dlx, dly,
                                        Pp, nullptr, nullptr, nullptr);

    k_reduce<<<512, 256, 0, stream>>>(Pp, inva, S1a, R2);

    // stage-2: 8 Poisson solves, write output with zero boundary
    k_mega<2><<<8, 1024, 0, stream>>>(Shi, Slo, nullptr, nullptr, DINV,
                                      R2, nullptr, nullptr, nullptr, nullptr,
                                      nullptr, out, nullptr, nullptr, nullptr);
}